// Round 7
// baseline (545.604 us; speedup 1.0000x reference)
//
#include <hip/hip_runtime.h>
#include <hip/hip_fp16.h>

typedef unsigned int u32;
typedef unsigned short u16;

#define N_NODES  100000
#define N_EDGES  1600000
#define N_GRAPHS 128

#define NPB      200        // nodes per bucket
#define NBUK     500        // buckets (500*200 = 100000)
#define CHUNK    8192       // edges per binning chunk
#define NCHUNK   196        // ceil(1600000/8192)
#define NHIST    (NBUK*NCHUNK)   // 98000
#define NBLKA    383        // ceil(98000/256)
#define NBN      196        // ceil(100000/512)

__device__ __forceinline__ float h2f(u16 h) { return __half2float(__ushort_as_half(h)); }
__device__ __forceinline__ u16 f2h(float f) { return __half_as_ushort(__float2half_rn(f)); }

// ---- per-chunk bucket histogram + per-graph node histogram ----
__global__ __launch_bounds__(512) void k_hist1(const int* __restrict__ dst, const int* __restrict__ batch,
                                               int* __restrict__ hist, int* __restrict__ bhist) {
    int t = threadIdx.x, b = blockIdx.x;
    if (b < NCHUNK) {
        __shared__ int lh[NBUK];
        for (int i = t; i < NBUK; i += 512) lh[i] = 0;
        __syncthreads();
        int base = b * CHUNK;
        #pragma unroll
        for (int it = 0; it < CHUNK / 512; ++it) {
            int e = base + it * 512 + t;
            if (e < N_EDGES) atomicAdd(&lh[dst[e] / NPB], 1);
        }
        __syncthreads();
        for (int i = t; i < NBUK; i += 512) hist[i * NCHUNK + b] = lh[i];
    } else {
        __shared__ int bh[N_GRAPHS];
        if (t < N_GRAPHS) bh[t] = 0;
        __syncthreads();
        int n = (b - NCHUNK) * 512 + t;
        if (n < N_NODES) atomicAdd(&bh[batch[n]], 1);
        __syncthreads();
        if (t < N_GRAPHS) atomicAdd(&bhist[t], bh[t]);
    }
}

// ---- scan stage 1: 256-element tile sums of hist ----
__global__ __launch_bounds__(256) void k_scanA1(const int* __restrict__ hist, int* __restrict__ asum) {
    __shared__ int sh[256];
    int t = threadIdx.x, i = blockIdx.x * 256 + t;
    sh[t] = (i < NHIST) ? hist[i] : 0;
    __syncthreads();
    for (int off = 128; off > 0; off >>= 1) {
        if (t < off) sh[t] += sh[t + off];
        __syncthreads();
    }
    if (t == 0) asum[blockIdx.x] = sh[0];
}

// ---- scan stage 2 (1 block): scan asum[383]; scan bhist[128] -> boff/bcur ----
__global__ __launch_bounds__(512) void k_scanA2(const int* __restrict__ asum, int* __restrict__ asumOff,
                                                const int* __restrict__ bhist, int* __restrict__ boff,
                                                int* __restrict__ bcur) {
    __shared__ int s1[512], s2[512];
    int t = threadIdx.x;
    int v = (t < NBLKA) ? asum[t] : 0;
    s1[t] = v; __syncthreads();
    int* pa = s1; int* pb = s2;
    for (int off = 1; off < 512; off <<= 1) {
        int x = pa[t];
        if (t >= off) x += pa[t - off];
        pb[t] = x; __syncthreads();
        int* tmp = pa; pa = pb; pb = tmp;
    }
    if (t < NBLKA) asumOff[t] = pa[t] - v;
    __syncthreads();
    int hv = (t < N_GRAPHS) ? bhist[t] : 0;
    pa[t] = hv; __syncthreads();
    int* qa = pa; int* qb = pb;
    for (int off = 1; off < 512; off <<= 1) {
        int x = qa[t];
        if (t >= off) x += qa[t - off];
        qb[t] = x; __syncthreads();
        int* tmp = qa; qa = qb; qb = tmp;
    }
    if (t < N_GRAPHS) { int e = qa[t] - hv; boff[t] = e; bcur[t] = e; }
    if (t == 0) boff[N_GRAPHS] = N_NODES;
}

// ---- scan stage 3: in-place exclusive scan of hist + global offsets ----
__global__ __launch_bounds__(256) void k_scanA3(int* __restrict__ hist, const int* __restrict__ asumOff) {
    __shared__ int s1[256], s2[256];
    int t = threadIdx.x, i = blockIdx.x * 256 + t;
    int v = (i < NHIST) ? hist[i] : 0;
    s1[t] = v; __syncthreads();
    int* pa = s1; int* pb = s2;
    for (int off = 1; off < 256; off <<= 1) {
        int x = pa[t];
        if (t >= off) x += pa[t - off];
        pb[t] = x; __syncthreads();
        int* tmp = pa; pa = pb; pb = tmp;
    }
    if (i < NHIST) hist[i] = pa[t] - v + asumOff[blockIdx.x];
}

// ---- bin edges into buckets (packed u32: dloc<<24 | src) + node sort-by-graph ----
__global__ __launch_bounds__(512) void k_bin(const int* __restrict__ src, const int* __restrict__ dst,
                                             const int* __restrict__ hist, u32* __restrict__ packed,
                                             const int* __restrict__ batch, int* __restrict__ bcur,
                                             int* __restrict__ nodeS) {
    int t = threadIdx.x, b = blockIdx.x;
    if (b < NCHUNK) {
        __shared__ int cur5[NBUK];
        for (int i = t; i < NBUK; i += 512) cur5[i] = hist[i * NCHUNK + b];
        __syncthreads();
        int base = b * CHUNK;
        #pragma unroll
        for (int it = 0; it < CHUNK / 512; ++it) {
            int e = base + it * 512 + t;
            if (e < N_EDGES) {
                int d = dst[e], s = src[e];
                int bk = d / NPB;
                int pos = atomicAdd(&cur5[bk], 1);
                packed[pos] = ((u32)(d - bk * NPB) << 24) | (u32)s;
            }
        }
    } else {
        int n = (b - NCHUNK) * 512 + t;
        if (n < N_NODES) {
            int pos = atomicAdd(&bcur[batch[n]], 1);
            nodeS[pos] = n;
        }
    }
}

// ---- per-bucket degree count -> dinv (dense) ----
__global__ __launch_bounds__(256) void k_degdinv(const u32* __restrict__ packed, const int* __restrict__ hist,
                                                 float* __restrict__ dinv) {
    __shared__ int cnt[NPB];
    int b = blockIdx.x, t = threadIdx.x;
    for (int i = t; i < NPB; i += 256) cnt[i] = 0;
    __syncthreads();
    int start = hist[b * NCHUNK];
    int end = (b == NBUK - 1) ? N_EDGES : hist[(b + 1) * NCHUNK];
    for (int i = start + t; i < end; i += 256) atomicAdd(&cnt[packed[i] >> 24], 1);
    __syncthreads();
    if (t < NPB) dinv[b * NPB + t] = rsqrtf((float)(cnt[t] + 1));
}

// ---- hs1 = fp16(dinv * (x @ W1)) ----
__global__ __launch_bounds__(256) void k_gemm1(const float* __restrict__ x, const float* __restrict__ W1,
                                               const float* __restrict__ dinv, u16* __restrict__ hs1) {
    __shared__ float w[128 * 16];
    __shared__ float xs[16][132];
    int t = threadIdx.x;
    {
        const float4* wv = (const float4*)W1;
        ((float4*)w)[t * 2]     = wv[t * 2];
        ((float4*)w)[t * 2 + 1] = wv[t * 2 + 1];
    }
    int base = blockIdx.x * 16;
    {
        const float4* xv = (const float4*)(x + (size_t)base * 128);
        #pragma unroll
        for (int q = 0; q < 2; ++q) {
            int i4 = t * 2 + q;
            float4 v = xv[i4];
            int idx = i4 * 4;
            *((float4*)&xs[idx >> 7][idx & 127]) = v;
        }
    }
    __syncthreads();
    int nl = t >> 4, j = t & 15;
    int n = base + nl;
    const float4* xr = (const float4*)&xs[nl][0];
    float acc = 0.f;
    #pragma unroll
    for (int k4 = 0; k4 < 32; ++k4) {
        float4 v = xr[k4];
        acc += v.x * w[(k4 * 4 + 0) * 16 + j];
        acc += v.y * w[(k4 * 4 + 1) * 16 + j];
        acc += v.z * w[(k4 * 4 + 2) * 16 + j];
        acc += v.w * w[(k4 * 4 + 3) * 16 + j];
    }
    hs1[n * 16 + j] = f2h(dinv[n] * acc);
}

// ---- bucket propagation: stream packed edges, gather fp16 rows, LDS-accumulate, dense merge ----
__global__ __launch_bounds__(512) void k_prop(const u32* __restrict__ packed, const int* __restrict__ hist,
                                              const u16* __restrict__ hs, float* __restrict__ pacc) {
    __shared__ float acc[NPB][17];
    int t = threadIdx.x;
    int b = blockIdx.x >> 1, half = blockIdx.x & 1;
    for (int i = t; i < NPB * 17; i += 512) (&acc[0][0])[i] = 0.f;
    __syncthreads();
    int start = hist[b * NCHUNK];
    int end = (b == NBUK - 1) ? N_EDGES : hist[(b + 1) * NCHUNK];
    int mid = start + ((end - start) >> 1);
    int r0 = half ? mid : start;
    int r1 = half ? end : mid;
    int g = t >> 2, q = t & 3;
    for (int i = r0 + g; i < r1; i += 128) {
        u32 p = packed[i];
        int dloc = (int)(p >> 24);
        int s = (int)(p & 0xFFFFFFu);
        ushort4 v = ((const ushort4*)hs)[s * 4 + q];
        int c = q * 4;
        atomicAdd(&acc[dloc][c + 0], h2f(v.x));
        atomicAdd(&acc[dloc][c + 1], h2f(v.y));
        atomicAdd(&acc[dloc][c + 2], h2f(v.z));
        atomicAdd(&acc[dloc][c + 3], h2f(v.w));
    }
    __syncthreads();
    int nb = b * NPB;
    for (int i = t; i < NPB * 16; i += 512) {
        int r = i >> 4, c = i & 15;
        float v = acc[r][c];
        if (v != 0.f) atomicAdd(&pacc[(nb + r) * 16 + c], v);
    }
}

// ---- epilogue 1: h1 = relu(dinv*(pacc + hs1) + b1); hs2 = fp16(dinv*h1); pacc = 0 (reuse) ----
__global__ __launch_bounds__(256) void k_epi1(float* __restrict__ pacc, const u16* __restrict__ hs1,
                                              const float* __restrict__ dinv, const float* __restrict__ b1,
                                              u16* __restrict__ hs2) {
    int gid = blockIdx.x * 256 + threadIdx.x;   // 1563 blocks: n*4+q groups
    int n = gid >> 2, q = gid & 3;
    if (n >= N_NODES) return;
    int base = n * 4 + q;                        // float4 / ushort4 index
    float4 pv = ((float4*)pacc)[base];
    ushort4 hv = ((const ushort4*)hs1)[base];
    float4 bb = ((const float4*)b1)[q];
    float dv = dinv[n];
    float h0 = fmaxf(dv * (pv.x + h2f(hv.x)) + bb.x, 0.f);
    float h1 = fmaxf(dv * (pv.y + h2f(hv.y)) + bb.y, 0.f);
    float h2 = fmaxf(dv * (pv.z + h2f(hv.z)) + bb.z, 0.f);
    float h3 = fmaxf(dv * (pv.w + h2f(hv.w)) + bb.w, 0.f);
    ushort4 o;
    o.x = f2h(dv * h0); o.y = f2h(dv * h1); o.z = f2h(dv * h2); o.w = f2h(dv * h3);
    ((ushort4*)hs2)[base] = o;
    float4 z = {0.f, 0.f, 0.f, 0.f};
    ((float4*)pacc)[base] = z;                   // re-zero for layer-2 accumulation
}

// ---- pooling: 64 sorted nodes/block, inline q2 = dinv*(pacc + hs2), segment-accumulate ----
__global__ __launch_bounds__(256) void k_pool(const float* __restrict__ pacc, const u16* __restrict__ hs2,
                                              const float* __restrict__ dinv,
                                              const float* __restrict__ W2, const float* __restrict__ b2,
                                              const int* __restrict__ nodeS, const int* __restrict__ batch,
                                              float* __restrict__ sums) {
    __shared__ float w[16 * 128];
    __shared__ float bsh[128];
    __shared__ float rows[64][16];
    __shared__ int   gid[64];
    int t = threadIdx.x;
    {
        const float4* wv = (const float4*)W2;
        ((float4*)w)[t * 2]     = wv[t * 2];
        ((float4*)w)[t * 2 + 1] = wv[t * 2 + 1];
    }
    if (t < 128) bsh[t] = b2[t];
    int base = blockIdx.x * 64;                 // 1563 blocks
    {
        int which = t >> 2, qq = t & 3;
        int idx = base + which;
        if (idx < N_NODES) {
            int node = nodeS[idx];
            if (qq == 0) gid[which] = batch[node];
            float dv = dinv[node];
            float4 pv = ((const float4*)pacc)[node * 4 + qq];
            ushort4 hv = ((const ushort4*)hs2)[node * 4 + qq];
            rows[which][qq * 4 + 0] = dv * (pv.x + h2f(hv.x));
            rows[which][qq * 4 + 1] = dv * (pv.y + h2f(hv.y));
            rows[which][qq * 4 + 2] = dv * (pv.z + h2f(hv.z));
            rows[which][qq * 4 + 3] = dv * (pv.w + h2f(hv.w));
        }
    }
    __syncthreads();
    int half = t >> 7, j = t & 127;
    float acc = 0.f;
    int curg = -1;
    for (int it = 0; it < 32; ++it) {
        int wh = half * 32 + it;
        int idx = base + wh;
        if (idx >= N_NODES) break;
        int g = gid[wh];
        if (g != curg) {
            if (curg >= 0) atomicAdd(&sums[curg * 128 + j], acc);
            curg = g; acc = 0.f;
        }
        float a = bsh[j];
        #pragma unroll
        for (int kk = 0; kk < 16; ++kk) a += rows[wh][kk] * w[kk * 128 + j];
        acc += fmaxf(a, 0.f);
    }
    if (curg >= 0) atomicAdd(&sums[curg * 128 + j], acc);
}

// ---- fused MLP head + log_softmax ----
__global__ __launch_bounds__(128) void k_head(const float* __restrict__ sums, const int* __restrict__ boff,
                                              const float* __restrict__ LW1, const float* __restrict__ Lb1,
                                              const float* __restrict__ LW2, const float* __restrict__ Lb2,
                                              float* __restrict__ out) {
    __shared__ float srow[128];
    __shared__ float z1s[128];
    __shared__ float zz[2];
    int g = blockIdx.x, t = threadIdx.x;
    int cnt = boff[g + 1] - boff[g];
    float rc = 1.0f / fmaxf((float)cnt, 1.0f);
    srow[t] = sums[g * 128 + t] * rc;
    __syncthreads();
    float a = Lb1[t];
    for (int k = 0; k < 128; ++k) a += srow[k] * LW1[k * 128 + t];
    z1s[t] = fmaxf(a, 0.f);
    __syncthreads();
    if (t < 2) {
        float z = Lb2[t];
        for (int jj = 0; jj < 128; ++jj) z += z1s[jj] * LW2[jj * 2 + t];
        zz[t] = z;
    }
    __syncthreads();
    if (t < 2) {
        float m = fmaxf(zz[0], zz[1]);
        float lse = m + logf(expf(zz[0] - m) + expf(zz[1] - m));
        out[g * 2 + t] = zz[t] - lse;
    }
}

extern "C" void kernel_launch(void* const* d_in, const int* in_sizes, int n_in,
                              void* d_out, int out_size, void* d_ws, size_t ws_size,
                              hipStream_t stream) {
    const float* x   = (const float*)d_in[0];
    const int* ei    = (const int*)d_in[1];
    const int* batch = (const int*)d_in[2];
    const float* W1  = (const float*)d_in[3];
    const float* b1  = (const float*)d_in[4];
    const float* W2  = (const float*)d_in[5];
    const float* b2  = (const float*)d_in[6];
    const float* LW1 = (const float*)d_in[7];
    const float* Lb1 = (const float*)d_in[8];
    const float* LW2 = (const float*)d_in[9];
    const float* Lb2 = (const float*)d_in[10];
    const int* src = ei;
    const int* dst = ei + N_EDGES;

    char* ws = (char*)d_ws;
    int*   bhist   = (int*)(ws);                  // 512 B
    float* sums    = (float*)(ws + 512);          // 65536 B
    float* pacc    = (float*)(ws + 66048);        // 6400000 B  [memset covers 0..6466048)
    int*   bcur    = (int*)(ws + 6466048);        // 512 B
    int*   boff    = (int*)(ws + 6466560);        // 1024 B (129 ints)
    int*   asum    = (int*)(ws + 6467584);        // 1536 B
    int*   asumOff = (int*)(ws + 6469120);        // 1536 B
    int*   hist    = (int*)(ws + 6470656);        // 392000 B (98000 ints)
    float* dinv    = (float*)(ws + 6862656);      // 400000 B
    int*   nodeS   = (int*)(ws + 7262656);        // 400000 B
    u32*   packed  = (u32*)(ws + 7662656);        // 6400000 B
    u16*   hs1     = (u16*)(ws + 14062656);       // 3200000 B (fp16)
    u16*   hs2     = (u16*)(ws + 17262656);       // 3200000 B (fp16)
    float* out     = (float*)d_out;

    // zero atomic targets: bhist + sums + pacc (contiguous prefix)
    hipMemsetAsync(ws, 0, 6466048, stream);

    k_hist1  <<<NCHUNK + NBN, 512, 0, stream>>>(dst, batch, hist, bhist);
    k_scanA1 <<<NBLKA,        256, 0, stream>>>(hist, asum);
    k_scanA2 <<<1,            512, 0, stream>>>(asum, asumOff, bhist, boff, bcur);
    k_scanA3 <<<NBLKA,        256, 0, stream>>>(hist, asumOff);
    k_bin    <<<NCHUNK + NBN, 512, 0, stream>>>(src, dst, hist, packed, batch, bcur, nodeS);
    k_degdinv<<<NBUK,         256, 0, stream>>>(packed, hist, dinv);
    k_gemm1  <<<6250,         256, 0, stream>>>(x, W1, dinv, hs1);
    k_prop   <<<2 * NBUK,     512, 0, stream>>>(packed, hist, hs1, pacc);
    k_epi1   <<<1563,         256, 0, stream>>>(pacc, hs1, dinv, b1, hs2);
    k_prop   <<<2 * NBUK,     512, 0, stream>>>(packed, hist, hs2, pacc);
    k_pool   <<<1563,         256, 0, stream>>>(pacc, hs2, dinv, W2, b2, nodeS, batch, sums);
    k_head   <<<128,          128, 0, stream>>>(sums, boff, LW1, Lb1, LW2, Lb2, out);
}

// Round 9
// 480.401 us; speedup vs baseline: 1.1357x; 1.1357x over previous
//
#include <hip/hip_runtime.h>
#include <hip/hip_fp16.h>

typedef unsigned int u32;
typedef unsigned short u16;

#define N_NODES  100000
#define N_EDGES  1600000
#define N_GRAPHS 128
#define NBE      6250       // 1600000/256
#define NBN      391        // ceil(100000/256)

__device__ __forceinline__ float h2f(u16 h) { return __half2float(__ushort_as_half(h)); }
__device__ __forceinline__ u16 f2h(float f) { return __half_as_ushort(__float2half_rn(f)); }

// ---- fused: degree histogram (global atomics) + per-graph node histogram (LDS-staged) ----
__global__ __launch_bounds__(256) void k_hist(const int* __restrict__ dst, const int* __restrict__ batch,
                                              int* __restrict__ deg, int* __restrict__ bhist) {
    int b = blockIdx.x;
    if (b < NBE) {
        int e = b * 256 + threadIdx.x;          // exact
        atomicAdd(&deg[dst[e]], 1);
    } else {
        __shared__ int bh[N_GRAPHS];
        int t = threadIdx.x;
        if (t < N_GRAPHS) bh[t] = 0;
        __syncthreads();
        int n = (b - NBE) * 256 + t;
        if (n < N_NODES) atomicAdd(&bh[batch[n]], 1);
        __syncthreads();
        if (t < N_GRAPHS && bh[t] > 0) atomicAdd(&bhist[t], bh[t]);
    }
}

// ---- 1 block: exclusive scan bhist[128] -> boff[129], bcur ----
__global__ __launch_bounds__(128) void k_scanB(const int* __restrict__ bhist, int* __restrict__ boff,
                                               int* __restrict__ bcur) {
    __shared__ int s1[128], s2[128];
    int t = threadIdx.x;
    int v = bhist[t];
    s1[t] = v; __syncthreads();
    int* pa = s1; int* pb = s2;
    for (int off = 1; off < 128; off <<= 1) {
        int x = pa[t];
        if (t >= off) x += pa[t - off];
        pb[t] = x; __syncthreads();
        int* tmp = pa; pa = pb; pb = tmp;
    }
    int excl = pa[t] - v;
    boff[t] = excl; bcur[t] = excl;
    if (t == 127) boff[128] = excl + v;        // = N_NODES
}

// ---- dinv (dense) + node sort-by-graph scatter ----
__global__ __launch_bounds__(256) void k_prep(const int* __restrict__ deg, const int* __restrict__ batch,
                                              float* __restrict__ dinv, int* __restrict__ bcur,
                                              int* __restrict__ nodeS) {
    int n = blockIdx.x * 256 + threadIdx.x;
    if (n < N_NODES) {
        dinv[n] = rsqrtf((float)(deg[n] + 1));
        int pos = atomicAdd(&bcur[batch[n]], 1);
        nodeS[pos] = n;
    }
}

// ---- hs1 = fp16(dinv * (x @ W1)) ----
__global__ __launch_bounds__(256) void k_gemm1(const float* __restrict__ x, const float* __restrict__ W1,
                                               const float* __restrict__ dinv, u16* __restrict__ hs1) {
    __shared__ float w[128 * 16];
    __shared__ float xs[16][132];
    int t = threadIdx.x;
    {
        const float4* wv = (const float4*)W1;
        ((float4*)w)[t * 2]     = wv[t * 2];
        ((float4*)w)[t * 2 + 1] = wv[t * 2 + 1];
    }
    int base = blockIdx.x * 16;
    {
        const float4* xv = (const float4*)(x + (size_t)base * 128);
        #pragma unroll
        for (int q = 0; q < 2; ++q) {
            int i4 = t * 2 + q;
            float4 v = xv[i4];
            int idx = i4 * 4;
            *((float4*)&xs[idx >> 7][idx & 127]) = v;
        }
    }
    __syncthreads();
    int nl = t >> 4, j = t & 15;
    int n = base + nl;
    const float4* xr = (const float4*)&xs[nl][0];
    float acc = 0.f;
    #pragma unroll
    for (int k4 = 0; k4 < 32; ++k4) {
        float4 v = xr[k4];
        acc += v.x * w[(k4 * 4 + 0) * 16 + j];
        acc += v.y * w[(k4 * 4 + 1) * 16 + j];
        acc += v.z * w[(k4 * 4 + 2) * 16 + j];
        acc += v.w * w[(k4 * 4 + 3) * 16 + j];
    }
    hs1[n * 16 + j] = f2h(dinv[n] * acc);
}

// ---- propagation: 8 lanes/edge, one packed-fp16 HW atomic each into L2-resident 3.2MB table ----
__global__ __launch_bounds__(256) void k_prop(const int* __restrict__ src, const int* __restrict__ dst,
                                              const __half2* __restrict__ hs, __half2* __restrict__ pacc) {
    int gid = blockIdx.x * 256 + threadIdx.x;   // 12,800,000 exactly (50000 blocks)
    int e = gid >> 3, h = gid & 7;
    int s = src[e], d = dst[e];
    __half2 v = hs[s * 8 + h];
    u32 bits; __builtin_memcpy(&bits, &v, 4);
    if (bits) unsafeAtomicAdd(&pacc[d * 8 + h], v);   // global_atomic_pk_add_f16
}

// ---- epilogue 1: h1 = relu(dinv*(pacc+hs1) + b1); hs2 = fp16(dinv*h1); pacc = 0 ----
__global__ __launch_bounds__(256) void k_epi1(u16* __restrict__ pacc, const u16* __restrict__ hs1,
                                              const float* __restrict__ dinv, const float* __restrict__ b1,
                                              u16* __restrict__ hs2) {
    int gid = blockIdx.x * 256 + threadIdx.x;   // 1563 blocks covers 400000
    int n = gid >> 2, q = gid & 3;
    if (n >= N_NODES) return;
    int base = n * 4 + q;                        // ushort4 index
    ushort4 pv = ((const ushort4*)pacc)[base];
    ushort4 hv = ((const ushort4*)hs1)[base];
    float4 bb = ((const float4*)b1)[q];
    float dv = dinv[n];
    float h0 = fmaxf(dv * (h2f(pv.x) + h2f(hv.x)) + bb.x, 0.f);
    float h1 = fmaxf(dv * (h2f(pv.y) + h2f(hv.y)) + bb.y, 0.f);
    float h2 = fmaxf(dv * (h2f(pv.z) + h2f(hv.z)) + bb.z, 0.f);
    float h3 = fmaxf(dv * (h2f(pv.w) + h2f(hv.w)) + bb.w, 0.f);
    ushort4 o;
    o.x = f2h(dv * h0); o.y = f2h(dv * h1); o.z = f2h(dv * h2); o.w = f2h(dv * h3);
    ((ushort4*)hs2)[base] = o;
    ushort4 z = {0, 0, 0, 0};
    ((ushort4*)pacc)[base] = z;                  // re-zero for layer-2 accumulation
}

// ---- pooling: 64 sorted nodes/block, inline q2 = dinv*(pacc+hs2), segment-accumulate ----
__global__ __launch_bounds__(256) void k_pool(const u16* __restrict__ pacc, const u16* __restrict__ hs2,
                                              const float* __restrict__ dinv,
                                              const float* __restrict__ W2, const float* __restrict__ b2,
                                              const int* __restrict__ nodeS, const int* __restrict__ batch,
                                              float* __restrict__ sums) {
    __shared__ float w[16 * 128];
    __shared__ float bsh[128];
    __shared__ float rows[64][16];
    __shared__ int   gid[64];
    int t = threadIdx.x;
    {
        const float4* wv = (const float4*)W2;
        ((float4*)w)[t * 2]     = wv[t * 2];
        ((float4*)w)[t * 2 + 1] = wv[t * 2 + 1];
    }
    if (t < 128) bsh[t] = b2[t];
    int base = blockIdx.x * 64;                 // 1563 blocks
    {
        int which = t >> 2, qq = t & 3;
        int idx = base + which;
        if (idx < N_NODES) {
            int node = nodeS[idx];
            if (qq == 0) gid[which] = batch[node];
            float dv = dinv[node];
            ushort4 pv = ((const ushort4*)pacc)[node * 4 + qq];
            ushort4 hv = ((const ushort4*)hs2)[node * 4 + qq];
            rows[which][qq * 4 + 0] = dv * (h2f(pv.x) + h2f(hv.x));
            rows[which][qq * 4 + 1] = dv * (h2f(pv.y) + h2f(hv.y));
            rows[which][qq * 4 + 2] = dv * (h2f(pv.z) + h2f(hv.z));
            rows[which][qq * 4 + 3] = dv * (h2f(pv.w) + h2f(hv.w));
        }
    }
    __syncthreads();
    int half = t >> 7, j = t & 127;
    float acc = 0.f;
    int curg = -1;
    for (int it = 0; it < 32; ++it) {
        int wh = half * 32 + it;
        int idx = base + wh;
        if (idx >= N_NODES) break;
        int g = gid[wh];
        if (g != curg) {
            if (curg >= 0) atomicAdd(&sums[curg * 128 + j], acc);
            curg = g; acc = 0.f;
        }
        float a = bsh[j];
        #pragma unroll
        for (int kk = 0; kk < 16; ++kk) a += rows[wh][kk] * w[kk * 128 + j];
        acc += fmaxf(a, 0.f);
    }
    if (curg >= 0) atomicAdd(&sums[curg * 128 + j], acc);
}

// ---- fused MLP head + log_softmax ----
__global__ __launch_bounds__(128) void k_head(const float* __restrict__ sums, const int* __restrict__ boff,
                                              const float* __restrict__ LW1, const float* __restrict__ Lb1,
                                              const float* __restrict__ LW2, const float* __restrict__ Lb2,
                                              float* __restrict__ out) {
    __shared__ float srow[128];
    __shared__ float z1s[128];
    __shared__ float zz[2];
    int g = blockIdx.x, t = threadIdx.x;
    int cnt = boff[g + 1] - boff[g];
    float rc = 1.0f / fmaxf((float)cnt, 1.0f);
    srow[t] = sums[g * 128 + t] * rc;
    __syncthreads();
    float a = Lb1[t];
    for (int k = 0; k < 128; ++k) a += srow[k] * LW1[k * 128 + t];
    z1s[t] = fmaxf(a, 0.f);
    __syncthreads();
    if (t < 2) {
        float z = Lb2[t];
        for (int jj = 0; jj < 128; ++jj) z += z1s[jj] * LW2[jj * 2 + t];
        zz[t] = z;
    }
    __syncthreads();
    if (t < 2) {
        float m = fmaxf(zz[0], zz[1]);
        float lse = m + logf(expf(zz[0] - m) + expf(zz[1] - m));
        out[g * 2 + t] = zz[t] - lse;
    }
}

extern "C" void kernel_launch(void* const* d_in, const int* in_sizes, int n_in,
                              void* d_out, int out_size, void* d_ws, size_t ws_size,
                              hipStream_t stream) {
    const float* x   = (const float*)d_in[0];
    const int* ei    = (const int*)d_in[1];
    const int* batch = (const int*)d_in[2];
    const float* W1  = (const float*)d_in[3];
    const float* b1  = (const float*)d_in[4];
    const float* W2  = (const float*)d_in[5];
    const float* b2  = (const float*)d_in[6];
    const float* LW1 = (const float*)d_in[7];
    const float* Lb1 = (const float*)d_in[8];
    const float* LW2 = (const float*)d_in[9];
    const float* Lb2 = (const float*)d_in[10];
    const int* src = ei;
    const int* dst = ei + N_EDGES;

    char* ws = (char*)d_ws;
    int*   bhist  = (int*)(ws);                   // 512 B
    float* sums   = (float*)(ws + 512);           // 65536 B
    int*   deg    = (int*)(ws + 66048);           // 400000 B
    u16*   paccH  = (u16*)(ws + 466048);          // 3200000 B (fp16 accum table, L2-resident)
    // ---- memset covers [0, 3666048) ----
    int*   boff   = (int*)(ws + 3666048);         // 1024 B (129 ints)
    int*   bcur   = (int*)(ws + 3667072);         // 512 B
    float* dinv   = (float*)(ws + 3667584);       // 400000 B
    int*   nodeS  = (int*)(ws + 4067584);         // 400000 B
    u16*   hs1    = (u16*)(ws + 4467584);         // 3200000 B
    u16*   hs2    = (u16*)(ws + 7667584);         // 3200000 B
    float* out    = (float*)d_out;

    (void)hipMemsetAsync(ws, 0, 3666048, stream);

    k_hist  <<<NBE + NBN, 256, 0, stream>>>(dst, batch, deg, bhist);
    k_scanB <<<1,         128, 0, stream>>>(bhist, boff, bcur);
    k_prep  <<<NBN,       256, 0, stream>>>(deg, batch, dinv, bcur, nodeS);
    k_gemm1 <<<6250,      256, 0, stream>>>(x, W1, dinv, hs1);
    k_prop  <<<50000,     256, 0, stream>>>(src, dst, (const __half2*)hs1, (__half2*)paccH);
    k_epi1  <<<1563,      256, 0, stream>>>(paccH, hs1, dinv, b1, hs2);
    k_prop  <<<50000,     256, 0, stream>>>(src, dst, (const __half2*)hs2, (__half2*)paccH);
    k_pool  <<<1563,      256, 0, stream>>>(paccH, hs2, dinv, W2, b2, nodeS, batch, sums);
    k_head  <<<128,       128, 0, stream>>>(sums, boff, LW1, Lb1, LW2, Lb2, out);
}